// Round 9
// baseline (211.410 us; speedup 1.0000x reference)
//
#include <hip/hip_runtime.h>
#include <stdint.h>
#include <math.h>

// pred_out [8,5,768,768] f32, target_mask [8,1,768,768] i32 (0..3), num_target_classes=4.
#define B_ 8
#define C_ 5
#define H_ 768
#define W_ 768
#define HW_ (H_*W_)
#define HWq (HW_/4)            // 147456 float4 per plane
#define NPIX (B_*HW_)          // 4,718,592
#define TB 8
#define INVAL 0xFFFFFFFFu
#define LN2F 0.69314718056f
#define BIASF 16.2f
#define TILE 32
#define TPR 24                 // tiles per row (W/32)
#define TPC 24                 // tile rows (H/32)
#define NTILES (B_*TPR*TPC)    // 4608
#define NPT 128                // border nodes per tile (4*32)
#define NNODES (NTILES*NPT)    // 589,824
#define SEAMS_PER_IMG (23*768) // 17664 per direction
#define NB_HALF (B_*SEAMS_PER_IMG)   // 141,312
#define NB_TOT (2*NB_HALF)           // 282,624
#define SEAMBLK (NB_TOT/256)         // 1104
#define NCOPY 32               // histogram replicas (2 lanes/copy: free 2-way aliasing)

typedef unsigned long long ull;

// ---------------- compact node union-find (lock-free, agent scope) -------------------------
static __device__ __forceinline__ unsigned pload(const unsigned* P, unsigned i) {
  return __hip_atomic_load(&P[i], __ATOMIC_RELAXED, __HIP_MEMORY_SCOPE_AGENT);
}
static __device__ unsigned findRootG(unsigned* P, unsigned i) {
  unsigned p = pload(P, i);
  if (p == i) return i;
  unsigned gp = pload(P, p);
  while (p != gp) {
    __hip_atomic_store(&P[i], gp, __ATOMIC_RELAXED, __HIP_MEMORY_SCOPE_AGENT);  // path halving
    i = p; p = gp; gp = pload(P, p);
  }
  return p;
}
static __device__ bool uniteG(unsigned* P, unsigned a, unsigned b) {
  a = findRootG(P, a);
  b = findRootG(P, b);
  while (a != b) {
    if (a < b) { unsigned t = a; a = b; b = t; }
    unsigned old = atomicCAS(&P[a], a, b);
    if (old == a) return true;     // one real merge
    a = findRootG(P, old);
    b = findRootG(P, b);
  }
  return false;
}
// ---------------- LDS union-find with high-16-bit payload (workgroup scope) ----------------
static __device__ __forceinline__ unsigned ploadL(const unsigned* P, unsigned i) {
  return __hip_atomic_load(&P[i], __ATOMIC_RELAXED, __HIP_MEMORY_SCOPE_WORKGROUP);
}
static __device__ unsigned findRootL(const unsigned* P, unsigned i) {
  unsigned p = ploadL(P, i) & 0xFFFFu;
  while (p != i) { i = p; p = ploadL(P, i) & 0xFFFFu; }
  return i;
}
static __device__ void uniteL(unsigned* P, unsigned a, unsigned b) {
  a = findRootL(P, a);
  b = findRootL(P, b);
  while (a != b) {
    if (a < b) { unsigned t = a; a = b; b = t; }
    unsigned old = atomicCAS(&P[a], 0xFFFF0000u | a, 0xFFFF0000u | b);
    if (old == (0xFFFF0000u | a)) return;
    a = findRootL(P, old & 0xFFFFu);
    b = findRootL(P, b);
  }
}

// ---------------- K1: fused stats + tile-CCL, 256 threads / 32x32 tile ---------------------
// hist word: [63:57] cnt | [56:38] sum pred*2^12 | [37:20] sum (logit+16.2)*2^6 | [16:0] sum mag*2^6
__global__ __launch_bounds__(256, 8) void k_stats_ccl(
    const float* __restrict__ pred, const int* __restrict__ tgt,
    unsigned short* __restrict__ border, unsigned* __restrict__ P2,
    unsigned* __restrict__ rootcnt, double* __restrict__ sp,
    unsigned* __restrict__ ctrl)
{
  __shared__ ull h[NCOPY][41];               // 10,496 B
  __shared__ unsigned lab[TILE*TILE];        // 4 KB (payload in high 16 bits)
  __shared__ unsigned lclsw[TILE*TILE/4];    // 1 KB
  __shared__ unsigned s_rt[4];
  unsigned char* lcls = (unsigned char*)lclsw;

  for (int i = threadIdx.x; i < NCOPY*41; i += 256) (&h[0][0])[i] = 0ull;
  if (threadIdx.x < 4) s_rt[threadIdx.x] = 0u;
  if (threadIdx.x < NPT) {
    unsigned n = (unsigned)blockIdx.x * NPT + threadIdx.x;
    P2[n] = n;
  }
  if (blockIdx.x == 0 && threadIdx.x == 0) ctrl[8] = 0u;  // done-counter for k2
  __syncthreads();

  const int cp = threadIdx.x & (NCOPY - 1);
  int blk = blockIdx.x;
  int b = blk / (TPR*TPC);
  int rem = blk - b * (TPR*TPC);
  int trow = rem / TPR;
  int ty0 = trow * TILE;
  int tx0 = (rem - trow * TPR) * TILE;

  // ---- load + stats phase: one quad per thread (wave covers 8 full 128B rows/instr) ----
  unsigned pk = 0u;
  {
    const int baseq = ty0 * (W_/4) + (tx0 >> 2);
    const int qrow = threadIdx.x >> 3, qcol = threadIdx.x & 7;
    const int o = qrow * (W_/4) + qcol;
    const float4* pp = (const float4*)pred + (size_t)b * (C_*HWq) + baseq + o;
    float4 a0 = pp[0];
    float4 a1 = pp[HWq];
    float4 a2 = pp[2*HWq];
    float4 a3 = pp[3*HWq];
    float4 a4 = pp[4*HWq];
    int4 t4 = ((const int4*)tgt)[(size_t)b * HWq + baseq + o];
#pragma unroll
    for (int j = 0; j < 4; ++j) {
      float v0 = ((const float*)&a0)[j];
      float v1 = ((const float*)&a1)[j];
      float v2 = ((const float*)&a2)[j];
      float v3 = ((const float*)&a3)[j];
      float v4 = ((const float*)&a4)[j];
      int tt = ((const int*)&t4)[j];
      float best = v0; int bc = 0;
      if (v1 > best) { best = v1; bc = 1; }
      if (v2 > best) { best = v2; bc = 2; }
      if (v3 > best) { best = v3; bc = 3; }
      if (v4 > best) { best = v4; bc = 4; }
      unsigned tu = (unsigned)tt; if (tu >= TB) tu = TB - 1;
      ull w;
      if (bc) {
        float pc = fminf(fmaxf(best, 1e-7f), 1.0f - 1e-7f);
        float l2p = __log2f(pc);
        float l2m = __log2f(1.0f - pc);
        float logit = (l2p - l2m) * LN2F;
        float mag   = -l2m * LN2F;
        w = (1ull << 57)
          | ((ull)__float2uint_rn(best * 4096.0f) << 38)
          | ((ull)__float2uint_rn((logit + BIASF) * 64.0f) << 20)
          | (ull)__float2uint_rn(mag * 64.0f);
      } else {
        w = 1ull << 57;
      }
      atomicAdd(&h[cp][(int)tu * C_ + bc], w);
      pk |= ((unsigned)bc) << (8 * j);
    }
    lclsw[threadIdx.x] = pk;
  }
  __syncthreads();

  // ---- CCL phase: thread owns its own 4-px quad ----
  const int r = threadIdx.x >> 3, sub = threadIdx.x & 7;
  const int seg = r * TILE + sub * 4;
  unsigned Dw = (r < TILE-1) ? lclsw[threadIdx.x + 8] : 0u;
  unsigned rb = (sub < 7) ? (lclsw[threadIdx.x + 1] & 255u) : 0u;
  {
    uint4 lw;
    unsigned* lp = (unsigned*)&lw;
#pragma unroll
    for (int k = 0; k < 4; ++k) {
      int li = seg + k;
      unsigned c = (pk >> (8 * k)) & 255u;
      lp[k] = c ? (0xFFFF0000u | (unsigned)li) : INVAL;
    }
    *(uint4*)&lab[seg] = lw;
  }
  __syncthreads();

#pragma unroll
  for (int j = 0; j < 4; ++j) {
    unsigned c = (pk >> (8 * j)) & 255u;
    if (!c) continue;
    int li = seg + j;
    unsigned cr = (j < 3) ? ((pk >> (8 * (j + 1))) & 255u) : rb;
    if (cr == c) uniteL(lab, li, li + 1);
    if (((Dw >> (8 * j)) & 255u) == c) uniteL(lab, li, li + TILE);
  }
  __syncthreads();

  {
    uint4 lw = *(const uint4*)&lab[seg];
    const unsigned* lp = (const unsigned*)&lw;
#pragma unroll
    for (int k = 0; k < 4; ++k) {
      int li = seg + k;
      unsigned c = (pk >> (8 * k)) & 255u;
      if (c && (lp[k] & 0xFFFFu) == (unsigned)li) atomicAdd(&s_rt[c - 1], 1u);
    }
  }
  // border representative election (low 16 bits of lab[root] invariant under atomicMin)
  unsigned bc_c = 0, bc_rt = 0;
  if (threadIdx.x < NPT) {
    int bp = threadIdx.x;
    int tx, ty;
    if (bp < 32)       { ty = 0;       tx = bp; }
    else if (bp < 64)  { ty = TILE-1;  tx = bp - 32; }
    else if (bp < 96)  { tx = 0;       ty = bp - 64; }
    else               { tx = TILE-1;  ty = bp - 96; }
    int li = ty * TILE + tx;
    bc_c = lcls[li];
    if (bc_c) {
      bc_rt = findRootL(lab, (unsigned)li);
      atomicMin(&lab[bc_rt], ((unsigned)threadIdx.x << 16) | bc_rt);
    }
  }
  __syncthreads();
  if (threadIdx.x < NPT) {
    unsigned sub2 = bc_c ? (lab[bc_rt] >> 16) : 0u;
    border[blk * NPT + threadIdx.x] = (unsigned short)((bc_c << 8) | sub2);
  }
  if (threadIdx.x < 4) rootcnt[blk * 4 + threadIdx.x] = s_rt[threadIdx.x];
  // histogram fold: 160 lanes, one (slot,component) each
  if (threadIdx.x < 160) {
    int slot = threadIdx.x >> 2, comp = threadIdx.x & 3;
    double s = 0.0;
#pragma unroll
    for (int cc = 0; cc < NCOPY; ++cc) {
      ull w = h[cc][slot];
      if (comp == 0)      s += (double)(w >> 57);
      else if (comp == 1) s += (double)((w >> 38) & 0x7FFFFull) * (1.0/4096.0);
      else if (comp == 2) s += (double)((w >> 20) & 0x3FFFFull) * (1.0/64.0);
      else                s += (double)(w & 0x1FFFFull) * (1.0/64.0);
    }
    sp[(size_t)blk * 160 + threadIdx.x] = s;
  }
}

// ---------------- K2: seam merge + sp reduction + last-block finalize ----------------------
#define SH_CNT(t,c)   shist[((t)*C_+(c))*4 + 0]
#define SH_PRED(t,c)  shist[((t)*C_+(c))*4 + 1]
#define SH_LRAW(t,c)  shist[((t)*C_+(c))*4 + 2]
#define SH_MAG(t,c)   shist[((t)*C_+(c))*4 + 3]
__global__ __launch_bounds__(256) void k_seam_final(
    const unsigned short* __restrict__ border, unsigned* __restrict__ P2,
    const double* __restrict__ sp, const unsigned* __restrict__ rootcnt,
    unsigned* __restrict__ smcnt, ull* __restrict__ spf_u,
    unsigned* __restrict__ ctrl, const int* __restrict__ ntcp,
    float* __restrict__ out)
{
  __shared__ unsigned s_sub[4];
  __shared__ double red[256];
  __shared__ int s_last;
  // finalize arrays (last block only)
  __shared__ double shist[160];
  __shared__ double s_col[C_][3];
  __shared__ unsigned s_cnti[TB*C_];
  __shared__ unsigned s_ctot[C_];
  __shared__ unsigned s_nc[4], s_smg[4];
  __shared__ float s_ph[C_];
  __shared__ double s_term[TB];
  __shared__ int s_NT;
  __shared__ int s_nun;

  if (threadIdx.x < 4) s_sub[threadIdx.x] = 0u;
  __syncthreads();
  int idx = blockIdx.x * blockDim.x + threadIdx.x;
  {
    int tA, tB, pA, pB;
    if (idx < NB_HALF) {             // down seams
      int b = idx / SEAMS_PER_IMG;
      int r = idx - b * SEAMS_PER_IMG;
      int seam = r / W_;             // 0..22
      int x = r - seam * W_;
      int tj = x >> 5, k = x & 31;
      tA = (b * TPC + seam) * TPR + tj;
      tB = tA + TPR;
      pA = tA * NPT + 32 + k;        // bottom row of tA
      pB = tB * NPT + 0 + k;         // top row of tB
    } else {                         // right seams
      int i2 = idx - NB_HALF;
      int b = i2 / SEAMS_PER_IMG;
      int r = i2 - b * SEAMS_PER_IMG;
      int seam = r / H_;             // 0..22
      int y = r - seam * H_;
      int ti = y >> 5, k = y & 31;
      tA = (b * TPC + ti) * TPR + seam;
      tB = tA + 1;
      pA = tA * NPT + 96 + k;        // right col of tA
      pB = tB * NPT + 64 + k;        // left col of tB
    }
    unsigned a16 = border[pA];
    unsigned b16 = border[pB];
    unsigned ca = a16 >> 8, cb = b16 >> 8;
    if (ca && ca == cb) {
      if (uniteG(P2, (unsigned)tA * NPT + (a16 & 255u),
                     (unsigned)tB * NPT + (b16 & 255u)))
        atomicAdd(&s_sub[ca - 1], 1u);
    }
  }
  // sp column reduction in blocks 0..159 (runs concurrently with seams elsewhere)
  if (blockIdx.x < 160) {
    double s = 0.0;
    for (int j = threadIdx.x; j < NTILES; j += 256) s += sp[(size_t)j * 160 + blockIdx.x];
    red[threadIdx.x] = s;
    __syncthreads();
    for (int off = 128; off; off >>= 1) {
      if (threadIdx.x < off) red[threadIdx.x] += red[threadIdx.x + off];
      __syncthreads();
    }
    if (threadIdx.x == 0)
      __hip_atomic_store(&spf_u[blockIdx.x], (ull)__double_as_longlong(red[0]),
                         __ATOMIC_RELAXED, __HIP_MEMORY_SCOPE_AGENT);
  }
  __syncthreads();
  if (threadIdx.x < 4)
    __hip_atomic_store(&smcnt[blockIdx.x * 4 + threadIdx.x], s_sub[threadIdx.x],
                       __ATOMIC_RELAXED, __HIP_MEMORY_SCOPE_AGENT);
  __syncthreads();   // drain all global stores/atomics before signaling done
  if (threadIdx.x == 0) {
    unsigned old = __hip_atomic_fetch_add(&ctrl[8], 1u,
                     __ATOMIC_RELAXED, __HIP_MEMORY_SCOPE_AGENT);
    s_last = (old == (unsigned)(SEAMBLK - 1));
  }
  __syncthreads();
  if (!s_last) return;

  // ================= finalize (exactly one block) =================
  if (threadIdx.x < 160) {
    ull u = __hip_atomic_load(&spf_u[threadIdx.x],
              __ATOMIC_RELAXED, __HIP_MEMORY_SCOPE_AGENT);
    shist[threadIdx.x] = __longlong_as_double((long long)u);
  }
  if (threadIdx.x < 4) { s_nc[threadIdx.x] = 0u; s_smg[threadIdx.x] = 0u; }
  if (threadIdx.x < TB) s_term[threadIdx.x] = 0.0;
  if (threadIdx.x == 0) {
    int NT = ntcp[0];
    if (NT < 1) NT = 1;
    if (NT > TB) NT = TB;
    s_NT = NT;
  }
  __syncthreads();
  {
    unsigned a = 0;
    for (int j = threadIdx.x; j < NTILES * 4; j += 256) a += rootcnt[j];  // j&3 fixed/thread
    if (a) atomicAdd(&s_nc[threadIdx.x & 3], a);
  }
  {
    unsigned a = 0;
    for (int j = threadIdx.x; j < SEAMBLK * 4; j += 256)
      a += __hip_atomic_load(&smcnt[j], __ATOMIC_RELAXED, __HIP_MEMORY_SCOPE_AGENT);
    if (a) atomicAdd(&s_smg[threadIdx.x & 3], a);
  }
  __syncthreads();

  if (threadIdx.x < TB * C_) s_cnti[threadIdx.x] = (unsigned)llrint(shist[threadIdx.x * 4]);
  __syncthreads();

  if (threadIdx.x < C_) {
    int c = threadIdx.x;
    double sc = 0.0, sp2 = 0.0, sl = 0.0;
    unsigned ct = 0;
#pragma unroll
    for (int t = 0; t < TB; ++t) {
      sc += SH_CNT(t, c);
      sp2 += SH_PRED(t, c);
      sl += -SH_MAG(t, c);
      ct += s_cnti[t * C_ + c];
    }
    s_col[c][0] = sc; s_col[c][1] = sp2; s_col[c][2] = sl;
    s_ctot[c] = ct;
  }
  __syncthreads();

  // ph_tab: exact f32 replay incl. int32 wrap of n_comp*last_i
  if (threadIdx.x == 0) {
#pragma unroll
    for (int cc = 0; cc < C_; ++cc) {
      float ph = 0.0f;
      int li = 1;
#pragma unroll
      for (int v = 1; v < C_; ++v) {
        unsigned ncv = s_nc[v - 1] - s_smg[v - 1];
        if (s_ctot[v] > 0) {
          int prod = (int)(ncv * (unsigned)li);
          float sv = (float)prod;
          float inc = ((cc == v) ? 1.0f : 0.0f) + sv;
          ph = ph + inc;
          li = li + (int)ncv + ((s_ctot[v] < (unsigned)NPIX) ? 1 : 0);
        }
      }
      s_ph[cc] = ph;
    }
  }
  __syncthreads();

  const float EPSF = 1e-7f;
  const double L1 = (double)logf(1.0f - EPSF);
  const double M1 = (double)log1pf(-(1.0f - EPSF));
  const double L0 = (double)logf(EPSF);
  const double M0 = (double)log1pf(-EPSF);
  const double N = (double)NPIX;
  const double BIASD = (double)BIASF;
  const int NT = s_NT;

  if (threadIdx.x == 0) {
    double nt0 = 0;
#pragma unroll
    for (int c = 0; c < C_; ++c) nt0 += SH_CNT(0, c);
    double np1 = (double)s_ctot[0];
    double n11 = SH_CNT(0, 0);
    s_term[0] = -(n11*L1 + (nt0 - n11)*L0 + (np1 - n11)*M1 + (N - nt0 - np1 + n11)*M0) / N
                + 1.0 - (2.0*n11 + 1.0) / (np1 + nt0 + 1.0);
    int nun = 0;
    for (int t = 0; t < NT; ++t) {
      long long s = 0;
#pragma unroll
      for (int c = 0; c < C_; ++c) s += (long long)s_cnti[t * C_ + c];
      if (s) nun++;
    }
    s_nun = nun;
  } else if (threadIdx.x < (unsigned)NT) {
    int t = threadIdx.x;
    long long ntti = 0;
#pragma unroll
    for (int c = 0; c < C_; ++c) ntti += (long long)s_cnti[t * C_ + c];
    if (ntti != 0) {
      double ntt = 0;
#pragma unroll
      for (int c = 0; c < C_; ++c) ntt += SH_CNT(t, c);
      float pht[C_] = {s_ph[0], s_ph[1], s_ph[2], s_ph[3], s_ph[4]};
      int idx2[C_] = {0, 1, 2, 3, 4};
#pragma unroll
      for (int i = 1; i < C_; ++i)
        for (int j = i; j > 0 && pht[idx2[j]] < pht[idx2[j-1]]; --j) {
          int tmp = idx2[j]; idx2[j] = idx2[j-1]; idx2[j-1] = tmp;
        }
      long long k = (ntti - 1) / 2;
      float med = pht[idx2[C_ - 1]];
      long long cum = 0;
#pragma unroll
      for (int i = 0; i < C_; ++i) {
        cum += (long long)s_cnti[t * C_ + idx2[i]];
        if (cum > k) { med = pht[idx2[i]]; break; }
      }
      double A = 0, Bt = 0, inter = 0, sum_p = 0, ex = 0, nfg_t = 0, nfg_all = 0;
#pragma unroll
      for (int c = 1; c < C_; ++c) {
        double cnt_tc = SH_CNT(t, c);
        double mag_tc = SH_MAG(t, c);
        double spred_tc = SH_PRED(t, c);
        if (pht[c] == med) {
          double logit = SH_LRAW(t, c) - BIASD * cnt_tc;
          A += logit - mag_tc;                 // logpc = logit + log1m
          inter += spred_tc;
          nfg_t += cnt_tc;
          nfg_all += s_col[c][0];
          sum_p += s_col[c][1];
          Bt += s_col[c][2] - (-mag_tc);       // sum over t2 != t of log1m
        } else {
          ex += spred_tc;
        }
      }
      double bce  = -(A + Bt + (ntt - nfg_t)*L0 + (N - ntt - (nfg_all - nfg_t))*M0) / N;
      double dice = 1.0 - (2.0*inter + 1.0) / (sum_p + ntt + 1.0);
      s_term[t] = bce + dice + ex / ntt;
    }
  }
  __syncthreads();
  if (threadIdx.x == 0) {
    double res = 0.0;
#pragma unroll
    for (int t = 0; t < TB; ++t) res += s_term[t];
    out[0] = (float)(res / (double)(2 * s_nun + 1));
  }
}

extern "C" void kernel_launch(void* const* d_in, const int* in_sizes, int n_in,
                              void* d_out, int out_size, void* d_ws, size_t ws_size,
                              hipStream_t stream) {
  const float* pred = (const float*)d_in[0];
  const int* tgt = (const int*)d_in[1];
  const int* ntc = (const int*)d_in[2];
  float* out = (float*)d_out;
  char* ws = (char*)d_ws;
  // ws layout: ctrl | spf_u | sp | P2 | border | rootcnt | smcnt  (~9.5 MB)
  size_t off = 0;
  unsigned* ctrl = (unsigned*)(ws + off);        off += 16 * 4;                     // 64
  ull* spf_u = (ull*)(ws + off);                 off += 160 * 8;                    // 1,280
  double* sp = (double*)(ws + off);              off += (size_t)NTILES * 160 * 8;   // 5,898,240
  unsigned* P2 = (unsigned*)(ws + off);          off += (size_t)NNODES * 4;         // 2,359,296
  unsigned short* border = (unsigned short*)(ws + off); off += (size_t)NTILES * NPT * 2; // 1,179,648
  unsigned* rootcnt = (unsigned*)(ws + off);     off += (size_t)NTILES * 4 * 4;     // 73,728
  unsigned* smcnt = (unsigned*)(ws + off);       off += (size_t)SEAMBLK * 4 * 4;    // 17,664

  hipLaunchKernelGGL(k_stats_ccl, dim3(NTILES), dim3(256), 0, stream,
                     pred, tgt, border, P2, rootcnt, sp, ctrl);
  hipLaunchKernelGGL(k_seam_final, dim3(SEAMBLK), dim3(256), 0, stream,
                     border, P2, sp, rootcnt, smcnt, spf_u, ctrl, ntc, out);
}

// Round 10
// 172.194 us; speedup vs baseline: 1.2277x; 1.2277x over previous
//
#include <hip/hip_runtime.h>
#include <stdint.h>
#include <math.h>

// pred_out [8,5,768,768] f32, target_mask [8,1,768,768] i32 (0..3), num_target_classes=4.
#define B_ 8
#define C_ 5
#define H_ 768
#define W_ 768
#define HW_ (H_*W_)
#define HWq (HW_/4)            // 147456 float4 per plane
#define NPIX (B_*HW_)          // 4,718,592
#define TB 8
#define INVAL 0xFFFFFFFFu
#define LN2F 0.69314718056f
#define BIASF 16.2f
#define TILE 32
#define TPR 24                 // tiles per row (W/32)
#define TPC 24                 // tile rows (H/32)
#define NTILES (B_*TPR*TPC)    // 4608
#define NPT 128                // border nodes per tile (4*32)
#define NNODES (NTILES*NPT)    // 589,824
#define SEAMS_PER_IMG (23*768) // 17664 per direction
#define NB_HALF (B_*SEAMS_PER_IMG)   // 141,312
#define NB_TOT (2*NB_HALF)           // 282,624
#define SEAMBLK (NB_TOT/256)         // 1104
#define NCOPY 16               // histogram replicas (overflow-safe: 16 thr * 4 px = 64 max/bucket)
#define REPS 8                 // global spu replicas
#define REPC 64                // global counter replicas

typedef unsigned long long ull;

// Accumulators OUTSIDE the poisoned workspace: zero-initialized at module load,
// re-zeroed by k_final after each use. Written with hardware u64/u32 atomics (exact
// integer fixed-point: cnt unit 1, pred unit 2^-12, lraw/mag unit 2^-6).
__device__ ull g_spu[REPS * 160];
__device__ unsigned g_crep[REPC * 16];   // [0..3]=rootcnt, [4..7]=seamcnt per replica

// ---------------- compact node union-find (lock-free, agent scope) -------------------------
static __device__ __forceinline__ unsigned pload(const unsigned* P, unsigned i) {
  return __hip_atomic_load(&P[i], __ATOMIC_RELAXED, __HIP_MEMORY_SCOPE_AGENT);
}
static __device__ unsigned findRootG(unsigned* P, unsigned i) {
  unsigned p = pload(P, i);
  if (p == i) return i;
  unsigned gp = pload(P, p);
  while (p != gp) {
    __hip_atomic_store(&P[i], gp, __ATOMIC_RELAXED, __HIP_MEMORY_SCOPE_AGENT);  // path halving
    i = p; p = gp; gp = pload(P, p);
  }
  return p;
}
static __device__ bool uniteG(unsigned* P, unsigned a, unsigned b) {
  a = findRootG(P, a);
  b = findRootG(P, b);
  while (a != b) {
    if (a < b) { unsigned t = a; a = b; b = t; }
    unsigned old = atomicCAS(&P[a], a, b);
    if (old == a) return true;     // one real merge
    a = findRootG(P, old);
    b = findRootG(P, b);
  }
  return false;
}
// ---------------- LDS union-find with high-16-bit payload (workgroup scope) ----------------
static __device__ __forceinline__ unsigned ploadL(const unsigned* P, unsigned i) {
  return __hip_atomic_load(&P[i], __ATOMIC_RELAXED, __HIP_MEMORY_SCOPE_WORKGROUP);
}
static __device__ unsigned findRootL(const unsigned* P, unsigned i) {
  unsigned p = ploadL(P, i) & 0xFFFFu;
  while (p != i) { i = p; p = ploadL(P, i) & 0xFFFFu; }
  return i;
}
static __device__ void uniteL(unsigned* P, unsigned a, unsigned b) {
  a = findRootL(P, a);
  b = findRootL(P, b);
  while (a != b) {
    if (a < b) { unsigned t = a; a = b; b = t; }
    unsigned old = atomicCAS(&P[a], 0xFFFF0000u | a, 0xFFFF0000u | b);
    if (old == (0xFFFF0000u | a)) return;
    a = findRootL(P, old & 0xFFFFu);
    b = findRootL(P, b);
  }
}

// ---------------- K1: fused stats + tile-CCL, 256 threads / 32x32 tile ---------------------
// hist word: [63:57] cnt | [56:38] sum pred*2^12 | [37:20] sum (logit+16.2)*2^6 | [16:0] sum mag*2^6
// Field-overflow safe: max 64 adds per copy-group bucket (cnt<=64, pred<=262144, lraw<=132288,
// mag<=66048 all within field widths).
__global__ __launch_bounds__(256, 8) void k_stats_ccl(
    const float* __restrict__ pred, const int* __restrict__ tgt,
    unsigned short* __restrict__ border, unsigned* __restrict__ P2)
{
  __shared__ ull h[NCOPY][41];               // 5,248 B
  __shared__ unsigned lab[TILE*TILE];        // 4 KB (payload in high 16 bits)
  __shared__ unsigned lclsw[TILE*TILE/4];    // 1 KB
  __shared__ unsigned s_rt[4];
  unsigned char* lcls = (unsigned char*)lclsw;

  for (int i = threadIdx.x; i < NCOPY*41; i += 256) (&h[0][0])[i] = 0ull;
  if (threadIdx.x < 4) s_rt[threadIdx.x] = 0u;
  if (threadIdx.x < NPT) {
    unsigned n = (unsigned)blockIdx.x * NPT + threadIdx.x;
    P2[n] = n;
  }
  __syncthreads();

  const int cp = threadIdx.x & (NCOPY - 1);
  int blk = blockIdx.x;
  int b = blk / (TPR*TPC);
  int rem = blk - b * (TPR*TPC);
  int trow = rem / TPR;
  int ty0 = trow * TILE;
  int tx0 = (rem - trow * TPR) * TILE;

  // ---- load + stats phase: one quad per thread (wave covers 8 full 128B rows/instr) ----
  unsigned pk = 0u;
  {
    const int baseq = ty0 * (W_/4) + (tx0 >> 2);
    const int qrow = threadIdx.x >> 3, qcol = threadIdx.x & 7;
    const int o = qrow * (W_/4) + qcol;
    const float4* pp = (const float4*)pred + (size_t)b * (C_*HWq) + baseq + o;
    float4 a0 = pp[0];
    float4 a1 = pp[HWq];
    float4 a2 = pp[2*HWq];
    float4 a3 = pp[3*HWq];
    float4 a4 = pp[4*HWq];
    int4 t4 = ((const int4*)tgt)[(size_t)b * HWq + baseq + o];
#pragma unroll
    for (int j = 0; j < 4; ++j) {
      float v0 = ((const float*)&a0)[j];
      float v1 = ((const float*)&a1)[j];
      float v2 = ((const float*)&a2)[j];
      float v3 = ((const float*)&a3)[j];
      float v4 = ((const float*)&a4)[j];
      int tt = ((const int*)&t4)[j];
      float best = v0; int bc = 0;
      if (v1 > best) { best = v1; bc = 1; }
      if (v2 > best) { best = v2; bc = 2; }
      if (v3 > best) { best = v3; bc = 3; }
      if (v4 > best) { best = v4; bc = 4; }
      unsigned tu = (unsigned)tt; if (tu >= TB) tu = TB - 1;
      ull w;
      if (bc) {
        float pc = fminf(fmaxf(best, 1e-7f), 1.0f - 1e-7f);
        float l2p = __log2f(pc);
        float l2m = __log2f(1.0f - pc);
        float logit = (l2p - l2m) * LN2F;
        float mag   = -l2m * LN2F;
        w = (1ull << 57)
          | ((ull)__float2uint_rn(best * 4096.0f) << 38)
          | ((ull)__float2uint_rn((logit + BIASF) * 64.0f) << 20)
          | (ull)__float2uint_rn(mag * 64.0f);
      } else {
        w = 1ull << 57;
      }
      atomicAdd(&h[cp][(int)tu * C_ + bc], w);
      pk |= ((unsigned)bc) << (8 * j);
    }
    lclsw[threadIdx.x] = pk;
  }
  __syncthreads();

  // ---- CCL phase: thread owns its own 4-px quad ----
  const int r = threadIdx.x >> 3, sub = threadIdx.x & 7;
  const int seg = r * TILE + sub * 4;
  unsigned Dw = (r < TILE-1) ? lclsw[threadIdx.x + 8] : 0u;
  unsigned rb = (sub < 7) ? (lclsw[threadIdx.x + 1] & 255u) : 0u;
  {
    uint4 lw;
    unsigned* lp = (unsigned*)&lw;
#pragma unroll
    for (int k = 0; k < 4; ++k) {
      int li = seg + k;
      unsigned c = (pk >> (8 * k)) & 255u;
      lp[k] = c ? (0xFFFF0000u | (unsigned)li) : INVAL;
    }
    *(uint4*)&lab[seg] = lw;
  }
  __syncthreads();

#pragma unroll
  for (int j = 0; j < 4; ++j) {
    unsigned c = (pk >> (8 * j)) & 255u;
    if (!c) continue;
    int li = seg + j;
    unsigned cr = (j < 3) ? ((pk >> (8 * (j + 1))) & 255u) : rb;
    if (cr == c) uniteL(lab, li, li + 1);
    if (((Dw >> (8 * j)) & 255u) == c) uniteL(lab, li, li + TILE);
  }
  __syncthreads();

  {
    uint4 lw = *(const uint4*)&lab[seg];
    const unsigned* lp = (const unsigned*)&lw;
#pragma unroll
    for (int k = 0; k < 4; ++k) {
      int li = seg + k;
      unsigned c = (pk >> (8 * k)) & 255u;
      if (c && (lp[k] & 0xFFFFu) == (unsigned)li) atomicAdd(&s_rt[c - 1], 1u);
    }
  }
  // border representative election (low 16 bits of lab[root] invariant under atomicMin)
  unsigned bc_c = 0, bc_rt = 0;
  if (threadIdx.x < NPT) {
    int bp = threadIdx.x;
    int tx, ty;
    if (bp < 32)       { ty = 0;       tx = bp; }
    else if (bp < 64)  { ty = TILE-1;  tx = bp - 32; }
    else if (bp < 96)  { tx = 0;       ty = bp - 64; }
    else               { tx = TILE-1;  ty = bp - 96; }
    int li = ty * TILE + tx;
    bc_c = lcls[li];
    if (bc_c) {
      bc_rt = findRootL(lab, (unsigned)li);
      atomicMin(&lab[bc_rt], ((unsigned)threadIdx.x << 16) | bc_rt);
    }
  }
  __syncthreads();
  if (threadIdx.x < NPT) {
    unsigned sub2 = bc_c ? (lab[bc_rt] >> 16) : 0u;
    border[blk * NPT + threadIdx.x] = (unsigned short)((bc_c << 8) | sub2);
  }
  if (threadIdx.x < 4 && s_rt[threadIdx.x])
    atomicAdd(&g_crep[(blk & (REPC-1)) * 16 + threadIdx.x], s_rt[threadIdx.x]);
  // histogram fold: pure-integer field sums -> one u64 atomic per (slot,comp) lane
  if (threadIdx.x < 160) {
    int slot = threadIdx.x >> 2, comp = threadIdx.x & 3;
    ull fs = 0;
#pragma unroll
    for (int cc = 0; cc < NCOPY; ++cc) {
      ull w = h[cc][slot];
      if (comp == 0)      fs += (w >> 57);
      else if (comp == 1) fs += (w >> 38) & 0x7FFFFull;
      else if (comp == 2) fs += (w >> 20) & 0x3FFFFull;
      else                fs += w & 0x1FFFFull;
    }
    if (fs) atomicAdd(&g_spu[(blk & (REPS-1)) * 160 + threadIdx.x], fs);
  }
}

// ---------------- K2: seam merge only --------------------------------------------------------
__global__ __launch_bounds__(256) void k_seam(const unsigned short* __restrict__ border,
                                              unsigned* __restrict__ P2)
{
  __shared__ unsigned s_sub[4];
  if (threadIdx.x < 4) s_sub[threadIdx.x] = 0u;
  __syncthreads();
  int idx = blockIdx.x * blockDim.x + threadIdx.x;
  {
    int tA, tB, pA, pB;
    if (idx < NB_HALF) {             // down seams
      int b = idx / SEAMS_PER_IMG;
      int r = idx - b * SEAMS_PER_IMG;
      int seam = r / W_;             // 0..22
      int x = r - seam * W_;
      int tj = x >> 5, k = x & 31;
      tA = (b * TPC + seam) * TPR + tj;
      tB = tA + TPR;
      pA = tA * NPT + 32 + k;        // bottom row of tA
      pB = tB * NPT + 0 + k;         // top row of tB
    } else {                         // right seams
      int i2 = idx - NB_HALF;
      int b = i2 / SEAMS_PER_IMG;
      int r = i2 - b * SEAMS_PER_IMG;
      int seam = r / H_;             // 0..22
      int y = r - seam * H_;
      int ti = y >> 5, k = y & 31;
      tA = (b * TPC + ti) * TPR + seam;
      tB = tA + 1;
      pA = tA * NPT + 96 + k;        // right col of tA
      pB = tB * NPT + 64 + k;        // left col of tB
    }
    unsigned a16 = border[pA];
    unsigned b16 = border[pB];
    unsigned ca = a16 >> 8, cb = b16 >> 8;
    if (ca && ca == cb) {
      if (uniteG(P2, (unsigned)tA * NPT + (a16 & 255u),
                     (unsigned)tB * NPT + (b16 & 255u)))
        atomicAdd(&s_sub[ca - 1], 1u);
    }
  }
  __syncthreads();
  if (threadIdx.x < 4 && s_sub[threadIdx.x])
    atomicAdd(&g_crep[(blockIdx.x & (REPC-1)) * 16 + 4 + threadIdx.x], s_sub[threadIdx.x]);
}

// ---------------- K3: finalize (1 block) + re-zero device globals for next iteration --------
#define SH_CNT(t,c)   shist[((t)*C_+(c))*4 + 0]
#define SH_PRED(t,c)  shist[((t)*C_+(c))*4 + 1]
#define SH_LRAW(t,c)  shist[((t)*C_+(c))*4 + 2]
#define SH_MAG(t,c)   shist[((t)*C_+(c))*4 + 3]
__global__ __launch_bounds__(256) void k_final(const int* __restrict__ ntcp,
                                               float* __restrict__ out)
{
  __shared__ double shist[160];
  __shared__ double s_col[C_][3];       // per-class colsums: 0=cnt, 1=pred, 2=log1m (signed)
  __shared__ unsigned s_cnti[TB*C_];
  __shared__ unsigned s_ctot[C_];
  __shared__ unsigned s_nc[4], s_smg[4];
  __shared__ float s_ph[C_];
  __shared__ double s_term[TB];
  __shared__ int s_NT;
  __shared__ int s_nun;

  if (threadIdx.x < 160) {
    ull acc = 0;
#pragma unroll
    for (int rp = 0; rp < REPS; ++rp) acc += g_spu[rp * 160 + threadIdx.x];
    int comp = threadIdx.x & 3;
    shist[threadIdx.x] = (comp == 0) ? (double)acc
                       : (comp == 1) ? (double)acc * (1.0/4096.0)
                                     : (double)acc * (1.0/64.0);
  }
  if (threadIdx.x < 8) {
    unsigned a = 0;
    for (int rp = 0; rp < REPC; ++rp) a += g_crep[rp * 16 + threadIdx.x];
    if (threadIdx.x < 4) s_nc[threadIdx.x] = a;
    else                 s_smg[threadIdx.x - 4] = a;
  }
  if (threadIdx.x < TB) s_term[threadIdx.x] = 0.0;
  if (threadIdx.x == 0) {
    int NT = ntcp[0];
    if (NT < 1) NT = 1;
    if (NT > TB) NT = TB;
    s_NT = NT;
  }
  __syncthreads();

  if (threadIdx.x < TB * C_) s_cnti[threadIdx.x] = (unsigned)llrint(shist[threadIdx.x * 4]);
  __syncthreads();

  if (threadIdx.x < C_) {
    int c = threadIdx.x;
    double sc = 0.0, sp2 = 0.0, sl = 0.0;
    unsigned ct = 0;
#pragma unroll
    for (int t = 0; t < TB; ++t) {
      sc += SH_CNT(t, c);
      sp2 += SH_PRED(t, c);
      sl += -SH_MAG(t, c);
      ct += s_cnti[t * C_ + c];
    }
    s_col[c][0] = sc; s_col[c][1] = sp2; s_col[c][2] = sl;
    s_ctot[c] = ct;
  }
  __syncthreads();

  // ph_tab: exact f32 replay incl. int32 wrap of n_comp*last_i
  if (threadIdx.x == 0) {
#pragma unroll
    for (int cc = 0; cc < C_; ++cc) {
      float ph = 0.0f;
      int li = 1;
#pragma unroll
      for (int v = 1; v < C_; ++v) {
        unsigned ncv = s_nc[v - 1] - s_smg[v - 1];
        if (s_ctot[v] > 0) {
          int prod = (int)(ncv * (unsigned)li);
          float sv = (float)prod;
          float inc = ((cc == v) ? 1.0f : 0.0f) + sv;
          ph = ph + inc;
          li = li + (int)ncv + ((s_ctot[v] < (unsigned)NPIX) ? 1 : 0);
        }
      }
      s_ph[cc] = ph;
    }
  }
  __syncthreads();

  const float EPSF = 1e-7f;
  const double L1 = (double)logf(1.0f - EPSF);
  const double M1 = (double)log1pf(-(1.0f - EPSF));
  const double L0 = (double)logf(EPSF);
  const double M0 = (double)log1pf(-EPSF);
  const double N = (double)NPIX;
  const double BIASD = (double)BIASF;
  const int NT = s_NT;

  if (threadIdx.x == 0) {
    double nt0 = 0;
#pragma unroll
    for (int c = 0; c < C_; ++c) nt0 += SH_CNT(0, c);
    double np1 = (double)s_ctot[0];
    double n11 = SH_CNT(0, 0);
    s_term[0] = -(n11*L1 + (nt0 - n11)*L0 + (np1 - n11)*M1 + (N - nt0 - np1 + n11)*M0) / N
                + 1.0 - (2.0*n11 + 1.0) / (np1 + nt0 + 1.0);
    int nun = 0;
    for (int t = 0; t < NT; ++t) {
      long long s = 0;
#pragma unroll
      for (int c = 0; c < C_; ++c) s += (long long)s_cnti[t * C_ + c];
      if (s) nun++;
    }
    s_nun = nun;
  } else if (threadIdx.x < (unsigned)NT) {
    int t = threadIdx.x;
    long long ntti = 0;
#pragma unroll
    for (int c = 0; c < C_; ++c) ntti += (long long)s_cnti[t * C_ + c];
    if (ntti != 0) {
      double ntt = 0;
#pragma unroll
      for (int c = 0; c < C_; ++c) ntt += SH_CNT(t, c);
      float pht[C_] = {s_ph[0], s_ph[1], s_ph[2], s_ph[3], s_ph[4]};
      int idx2[C_] = {0, 1, 2, 3, 4};
#pragma unroll
      for (int i = 1; i < C_; ++i)
        for (int j = i; j > 0 && pht[idx2[j]] < pht[idx2[j-1]]; --j) {
          int tmp = idx2[j]; idx2[j] = idx2[j-1]; idx2[j-1] = tmp;
        }
      long long k = (ntti - 1) / 2;
      float med = pht[idx2[C_ - 1]];
      long long cum = 0;
#pragma unroll
      for (int i = 0; i < C_; ++i) {
        cum += (long long)s_cnti[t * C_ + idx2[i]];
        if (cum > k) { med = pht[idx2[i]]; break; }
      }
      double A = 0, Bt = 0, inter = 0, sum_p = 0, ex = 0, nfg_t = 0, nfg_all = 0;
#pragma unroll
      for (int c = 1; c < C_; ++c) {
        double cnt_tc = SH_CNT(t, c);
        double mag_tc = SH_MAG(t, c);
        double spred_tc = SH_PRED(t, c);
        if (pht[c] == med) {
          double logit = SH_LRAW(t, c) - BIASD * cnt_tc;
          A += logit - mag_tc;                 // logpc = logit + log1m
          inter += spred_tc;
          nfg_t += cnt_tc;
          nfg_all += s_col[c][0];
          sum_p += s_col[c][1];
          Bt += s_col[c][2] - (-mag_tc);       // sum over t2 != t of log1m
        } else {
          ex += spred_tc;
        }
      }
      double bce  = -(A + Bt + (ntt - nfg_t)*L0 + (N - ntt - (nfg_all - nfg_t))*M0) / N;
      double dice = 1.0 - (2.0*inter + 1.0) / (sum_p + ntt + 1.0);
      s_term[t] = bce + dice + ex / ntt;
    }
  }
  __syncthreads();
  if (threadIdx.x == 0) {
    double res = 0.0;
#pragma unroll
    for (int t = 0; t < TB; ++t) res += s_term[t];
    out[0] = (float)(res / (double)(2 * s_nun + 1));
  }
  // re-zero device-global accumulators for the next iteration (all reads are done)
  __syncthreads();
  for (int i = threadIdx.x; i < REPS * 160; i += 256) g_spu[i] = 0ull;
  for (int i = threadIdx.x; i < REPC * 16; i += 256) g_crep[i] = 0u;
}

extern "C" void kernel_launch(void* const* d_in, const int* in_sizes, int n_in,
                              void* d_out, int out_size, void* d_ws, size_t ws_size,
                              hipStream_t stream) {
  const float* pred = (const float*)d_in[0];
  const int* tgt = (const int*)d_in[1];
  const int* ntc = (const int*)d_in[2];
  float* out = (float*)d_out;
  char* ws = (char*)d_ws;
  // ws layout: P2 | border  (~3.5 MB; accumulators live in __device__ globals)
  size_t off = 0;
  unsigned* P2 = (unsigned*)(ws + off);          off += (size_t)NNODES * 4;         // 2,359,296
  unsigned short* border = (unsigned short*)(ws + off); off += (size_t)NTILES * NPT * 2; // 1,179,648

  hipLaunchKernelGGL(k_stats_ccl, dim3(NTILES), dim3(256), 0, stream,
                     pred, tgt, border, P2);
  hipLaunchKernelGGL(k_seam, dim3(SEAMBLK), dim3(256), 0, stream, border, P2);
  hipLaunchKernelGGL(k_final, dim3(1), dim3(256), 0, stream, ntc, out);
}